// Round 8
// baseline (1277.901 us; speedup 1.0000x reference)
//
#include <hip/hip_runtime.h>
#include <math.h>

#define BATCH 2
#define NHEAD 16
#define SEQ   2048
#define HD    64
#define EMB   1024

typedef float v2f __attribute__((ext_vector_type(2)));

// Compiler-only memory fence: forbids reordering LDS ops across phases.
// (r7 post-mortem: inlined __restrict__ LDS pointers + zero barriers let the
// scheduler hoist next-level ds_reads above prev-level ds_writes. Hardware
// LDS is in-order per wave, so a compile-time fence is sufficient.)
#define LDS_FENCE() asm volatile("" ::: "memory")

// ---------------------------------------------------------------------------
// Eigen-AVX-emulating f32 GEMM (DECISION PATH — arithmetic frozen, r6-proven):
// per element: 4 k-panels of 256, sequential mul-then-add within panel,
// panels summed in order, + bias. contract(off) forbids FMA fusion; float2
// packing pairs independent j-chains (bit-neutral per element, IEEE per lane).
// ---------------------------------------------------------------------------
template<int MODE>
__global__ __launch_bounds__(256)
void gemm_eigen(const float* __restrict__ A, const float* __restrict__ W,
                const float* __restrict__ bias, float* __restrict__ out) {
#pragma clang fp contract(off)
  __shared__ float As[16][68];
  __shared__ float Bs[16][68];
  const int m0 = blockIdx.x * 64;
  const int n0 = blockIdx.y * 64;
  const int t  = threadIdx.x;
  const int tx = t & 15, ty = t >> 4;
  const int ar = t >> 2, ac = (t & 3) * 4;
  const int br = t >> 4, bc = (t & 15) * 4;

  v2f tot[4][2] = {};
  v2f acc[4][2] = {};
  const v2f zero2 = {0.f, 0.f};

  for (int p = 0; p < 4; ++p) {            // 4 balanced k-panels of 256
    for (int kt = 0; kt < 16; ++kt) {
      const int k0 = p * 256 + kt * 16;
      float4 av = *(const float4*)&A[(size_t)(m0 + ar) * EMB + k0 + ac];
      *(float4*)&Bs[br][bc] = *(const float4*)&W[(size_t)(k0 + br) * EMB + n0 + bc];
      As[ac + 0][ar] = av.x;
      As[ac + 1][ar] = av.y;
      As[ac + 2][ar] = av.z;
      As[ac + 3][ar] = av.w;
      __syncthreads();
#pragma unroll
      for (int kk = 0; kk < 16; ++kk) {
        float4 a = *(const float4*)&As[kk][ty * 4];
        float4 b = *(const float4*)&Bs[kk][tx * 4];
        v2f b01; b01.x = b.x; b01.y = b.y;
        v2f b23; b23.x = b.z; b23.y = b.w;
        float aa[4] = {a.x, a.y, a.z, a.w};
#pragma unroll
        for (int i = 0; i < 4; ++i) {
          v2f avv; avv.x = aa[i]; avv.y = aa[i];
          acc[i][0] = acc[i][0] + avv * b01;   // contract off: mul, then add
          acc[i][1] = acc[i][1] + avv * b23;
        }
      }
      __syncthreads();
    }
#pragma unroll
    for (int i = 0; i < 4; ++i)
#pragma unroll
      for (int jp = 0; jp < 2; ++jp) {
        tot[i][jp] = tot[i][jp] + acc[i][jp];  // panel sums in order
        acc[i][jp] = zero2;
      }
  }

#pragma unroll
  for (int i = 0; i < 4; ++i) {
    const int m = m0 + ty * 4 + i;
#pragma unroll
    for (int j = 0; j < 4; ++j) {
      const int n = n0 + tx * 4 + j;
      const float val = tot[i][j >> 1][j & 1] + bias[n];
      if (MODE == 0) {
        out[(size_t)m * EMB + n] = val;
      } else {
        const int b = m >> 11, s = m & (SEQ - 1);
        const int h = n >> 6,  d = n & (HD - 1);
        out[((((size_t)b * NHEAD + h) * SEQ) + s) * HD + d] = val;
      }
    }
  }
}

// ---------------------------------------------------------------------------
// FMA f32 GEMM (VALUE PATH — v and out projections; precision-free).
// Default fp-contract fuses a*b+c -> packed fma: ~2x the eigen rate.
// ---------------------------------------------------------------------------
template<int MODE>
__global__ __launch_bounds__(256)
void gemm_fma(const float* __restrict__ A, const float* __restrict__ W,
              const float* __restrict__ bias, float* __restrict__ out) {
  __shared__ float As[16][68];
  __shared__ float Bs[16][68];
  const int m0 = blockIdx.x * 64;
  const int n0 = blockIdx.y * 64;
  const int t  = threadIdx.x;
  const int tx = t & 15, ty = t >> 4;
  const int ar = t >> 2, ac = (t & 3) * 4;
  const int br = t >> 4, bc = (t & 15) * 4;

  v2f acc[4][2] = {};

  for (int k0 = 0; k0 < EMB; k0 += 16) {
    float4 av = *(const float4*)&A[(size_t)(m0 + ar) * EMB + k0 + ac];
    *(float4*)&Bs[br][bc] = *(const float4*)&W[(size_t)(k0 + br) * EMB + n0 + bc];
    As[ac + 0][ar] = av.x;
    As[ac + 1][ar] = av.y;
    As[ac + 2][ar] = av.z;
    As[ac + 3][ar] = av.w;
    __syncthreads();
#pragma unroll
    for (int kk = 0; kk < 16; ++kk) {
      float4 a = *(const float4*)&As[kk][ty * 4];
      float4 b = *(const float4*)&Bs[kk][tx * 4];
      v2f b01; b01.x = b.x; b01.y = b.y;
      v2f b23; b23.x = b.z; b23.y = b.w;
      float aa[4] = {a.x, a.y, a.z, a.w};
#pragma unroll
      for (int i = 0; i < 4; ++i) {
        v2f avv; avv.x = aa[i]; avv.y = aa[i];
        acc[i][0] = acc[i][0] + avv * b01;   // contracts to fma
        acc[i][1] = acc[i][1] + avv * b23;
      }
    }
    __syncthreads();
  }

#pragma unroll
  for (int i = 0; i < 4; ++i) {
    const int m = m0 + ty * 4 + i;
#pragma unroll
    for (int j = 0; j < 4; ++j) {
      const int n = n0 + tx * 4 + j;
      const float val = acc[i][j >> 1][j & 1] + bias[n];
      if (MODE == 0) {
        out[(size_t)m * EMB + n] = val;
      } else {
        const int b = m >> 11, s = m & (SEQ - 1);
        const int h = n >> 6,  d = n & (HD - 1);
        out[((((size_t)b * NHEAD + h) * SEQ) + s) * HD + d] = val;
      }
    }
  }
}

// ---------------------------------------------------------------------------
// Pruning + sparse attention, wave-parallel. One wave = 4 queries; block =
// 4 waves = 16 queries of one (b,h). Decision arithmetic byte-identical to
// r6: level-0 sequential mul+add, level/final dots sequential FMA (d asc),
// top-k = butterfly argmax (value desc, index asc) == serial scan (total
// order => associative/commutative; empirically r2==r3). LDS state is
// wave-private; ordering enforced by LDS_FENCE at every phase boundary.
// NO __restrict__ anywhere on LDS-derived pointers (r7 post-mortem).
// ---------------------------------------------------------------------------
__device__ __forceinline__ float dot_fma64(const float* qrow, const float* kr) {
  float sc = 0.f;
#pragma unroll
  for (int u = 0; u < 16; ++u) {
    const float4 kv = *(const float4*)&kr[u * 4];
    const float4 qv = *(const float4*)&qrow[u * 4];
    sc = fmaf(qv.x, kv.x, sc);
    sc = fmaf(qv.y, kv.y, sc);
    sc = fmaf(qv.z, kv.z, sc);
    sc = fmaf(qv.w, kv.w, sc);
  }
  return sc;
}

template<int CS>
__device__ __forceinline__ void prune_level(const float* kb, const float* qrow,
                                            int qi, int c,
                                            const short* cur, short* nxt) {
  const int rep = cur[qi * 256 + c * CS + (CS >> 1)];
  const float sc = dot_fma64(qrow, kb + (size_t)rep * HD);
  float sv = sc;
#pragma unroll
  for (int r = 0; r < 8; ++r) {
    float v0 = sv; int i0 = c;
#pragma unroll
    for (int off = 1; off < 16; off <<= 1) {
      const float v1 = __shfl_xor(v0, off);
      const int   i1 = __shfl_xor(i0, off);
      if (v1 > v0 || (v1 == v0 && i1 < i0)) { v0 = v1; i0 = i1; }
    }
    if (c < CS) nxt[qi * 256 + r * CS + c] = cur[qi * 256 + i0 * CS + c];
    if (c == i0) sv = -INFINITY;
  }
}

__global__ __launch_bounds__(256)
void prune_attn3(const float* q, const float* k,
                 const float* v, float* ctx) {
  const int blk  = blockIdx.x;            // 0..4095
  const int tile = blk & 127;             // 16-query tile within (b,h)
  const int bh   = blk >> 7;
  const int wv   = threadIdx.x >> 6;
  const int lane = threadIdx.x & 63;
  const int qg   = wv * 4;                // this wave's query-slot base
  const int s0   = tile * 16 + qg;        // first seq pos of this wave

  const float* kb = k + (size_t)bh * SEQ * HD;
  const float* vb = v + (size_t)bh * SEQ * HD;
  const float* qb = q + ((size_t)bh * SEQ + s0) * HD;

  __shared__ float q_lds[16][68];         // row stride 272B (16B aligned)
  __shared__ short idx_a[16 * 256];
  __shared__ short idx_b[16 * 256];

#pragma unroll
  for (int qq = 0; qq < 4; ++qq)
    q_lds[qg + qq][lane] = qb[(size_t)qq * HD + lane];
  LDS_FENCE();

  // ---- level 0: lane = chunk, 4 query chains interleaved (mul+add, d asc) ----
  float sc0[4] = {0.f, 0.f, 0.f, 0.f};
  {
    const float* krep = kb + (size_t)(lane * 32 + 16) * HD;
#pragma unroll
    for (int u = 0; u < 16; ++u) {
      const float4 kv = *(const float4*)&krep[u * 4];
#pragma unroll
      for (int qq = 0; qq < 4; ++qq) {
        const float4 qv = *(const float4*)&q_lds[qg + qq][u * 4];
        sc0[qq] = __fadd_rn(sc0[qq], __fmul_rn(qv.x, kv.x));
        sc0[qq] = __fadd_rn(sc0[qq], __fmul_rn(qv.y, kv.y));
        sc0[qq] = __fadd_rn(sc0[qq], __fmul_rn(qv.z, kv.z));
        sc0[qq] = __fadd_rn(sc0[qq], __fmul_rn(qv.w, kv.w));
      }
    }
  }

  // ---- top-8 of 64 per query (butterfly == serial scan) + idx fill ----
#pragma unroll
  for (int qq = 0; qq < 4; ++qq) {
    float sv = sc0[qq];
#pragma unroll
    for (int r = 0; r < 8; ++r) {
      float v0 = sv; int i0 = lane;
#pragma unroll
      for (int off = 32; off; off >>= 1) {
        const float v1 = __shfl_xor(v0, off);
        const int   i1 = __shfl_xor(i0, off);
        if (v1 > v0 || (v1 == v0 && i1 < i0)) { v0 = v1; i0 = i1; }
      }
      if (lane < 32) idx_a[(qg + qq) * 256 + r * 32 + lane] = (short)(i0 * 32 + lane);
      if (lane == i0) sv = -INFINITY;
    }
  }
  LDS_FENCE();

  // ---- pruning levels: lane = (query, candidate) ----
  const int qq2  = lane >> 4;
  const int c    = lane & 15;
  const int qi   = qg + qq2;
  const float* qrow = &q_lds[qi][0];

  prune_level<16>(kb, qrow, qi, c, idx_a, idx_b);
  LDS_FENCE();
  prune_level< 8>(kb, qrow, qi, c, idx_b, idx_a);
  LDS_FENCE();
  prune_level< 4>(kb, qrow, qi, c, idx_a, idx_b);
  LDS_FENCE();
  prune_level< 2>(kb, qrow, qi, c, idx_b, idx_a);
  LDS_FENCE();

  // ---- final: 16 keys, sequential FMA dot, scale 1/8 ----
  const int kidx = idx_a[qi * 256 + c];
  const float sfin = __fmul_rn(dot_fma64(qrow, kb + (size_t)kidx * HD), 0.125f);

  // ---- softmax over each 16-lane group (value path; butterfly sum is
  //      uniform across the group since fadd is commutative pairwise) ----
  float mx = sfin;
#pragma unroll
  for (int off = 1; off < 16; off <<= 1) mx = fmaxf(mx, __shfl_xor(mx, off));
  const float e = expf(sfin - mx);
  float sum = e;
#pragma unroll
  for (int off = 1; off < 16; off <<= 1) sum += __shfl_xor(sum, off);

  // ---- PV: 4 query passes, lane owns dim d; coalesced 256B v-rows ----
  float accv[4];
#pragma unroll
  for (int qq = 0; qq < 4; ++qq) {
    float acc = 0.f;
#pragma unroll
    for (int j = 0; j < 16; ++j) {
      const float ej = __shfl(e,    qq * 16 + j);
      const float sm = __shfl(sum,  qq * 16 + j);
      const int   kj = __shfl(kidx, qq * 16 + j);
      acc = fmaf(__fdiv_rn(ej, sm), vb[(size_t)kj * HD + lane], acc);
    }
    accv[qq] = acc;
  }

  const int b = bh >> 4, h = bh & 15;
#pragma unroll
  for (int qq = 0; qq < 4; ++qq)
    ctx[((size_t)b * SEQ + (s0 + qq)) * EMB + h * HD + lane] = accv[qq];
}

// ---------------------------------------------------------------------------
extern "C" void kernel_launch(void* const* d_in, const int* in_sizes, int n_in,
                              void* d_out, int out_size, void* d_ws, size_t ws_size,
                              hipStream_t stream) {
  const float* x  = (const float*)d_in[0];
  const float* Wq = (const float*)d_in[1];
  const float* bq = (const float*)d_in[2];
  const float* Wk = (const float*)d_in[3];
  const float* bk = (const float*)d_in[4];
  const float* Wv = (const float*)d_in[5];
  const float* bv = (const float*)d_in[6];
  const float* Wo = (const float*)d_in[7];
  const float* bo = (const float*)d_in[8];
  float* out = (float*)d_out;

  const size_t SZ = (size_t)BATCH * NHEAD * SEQ * HD;  // 4,194,304
  float* qw = (float*)d_ws;
  float* kw = qw + SZ;
  float* vw = kw + SZ;
  float* cw = vw + SZ;   // ctx in [B,S,E] layout

  dim3 g(64, 16), blk(256);
  gemm_eigen<1><<<g, blk, 0, stream>>>(x, Wq, bq, qw);
  gemm_eigen<1><<<g, blk, 0, stream>>>(x, Wk, bk, kw);
  gemm_fma<1><<<g, blk, 0, stream>>>(x, Wv, bv, vw);
  prune_attn3<<<dim3(BATCH * NHEAD * (SEQ / 16)), blk, 0, stream>>>(qw, kw, vw, cw);
  gemm_fma<0><<<g, blk, 0, stream>>>(cw, Wo, bo, out);
}

// Round 9
// 728.683 us; speedup vs baseline: 1.7537x; 1.7537x over previous
//
#include <hip/hip_runtime.h>
#include <math.h>

#define BATCH 2
#define NHEAD 16
#define SEQ   2048
#define HD    64
#define EMB   1024

// Compiler-only memory fence: forbids reordering LDS ops across phases
// (r7 post-mortem: without it, inlined LDS pointers let the scheduler hoist
// next-phase ds_reads above prev-phase ds_writes; wave-private LDS needs
// only a compile-time fence, hardware is in-order per wave).
#define LDS_FENCE() asm volatile("" ::: "memory")

// ---------------------------------------------------------------------------
// Eigen-AVX-emulating f32 GEMM (DECISION PATH — arithmetic frozen, r6-proven
// verbatim): 4 k-panels of 256, sequential mul-then-add within panel, panels
// summed in order, + bias. __fmul_rn/__fadd_rn defeat fp-contract.
// ---------------------------------------------------------------------------
template<int MODE>
__global__ __launch_bounds__(256)
void gemm_eigen(const float* __restrict__ A, const float* __restrict__ W,
                const float* __restrict__ bias, float* __restrict__ out) {
  __shared__ float As[16][68];
  __shared__ float Bs[16][68];
  const int m0 = blockIdx.x * 64;
  const int n0 = blockIdx.y * 64;
  const int t  = threadIdx.x;
  const int tx = t & 15, ty = t >> 4;
  const int ar = t >> 2, ac = (t & 3) * 4;
  const int br = t >> 4, bc = (t & 15) * 4;

  float tot[4][4] = {};
  float acc[4][4] = {};

  for (int p = 0; p < 4; ++p) {            // 4 balanced k-panels of 256
    for (int kt = 0; kt < 16; ++kt) {
      const int k0 = p * 256 + kt * 16;
      float4 av = *(const float4*)&A[(size_t)(m0 + ar) * EMB + k0 + ac];
      *(float4*)&Bs[br][bc] = *(const float4*)&W[(size_t)(k0 + br) * EMB + n0 + bc];
      As[ac + 0][ar] = av.x;
      As[ac + 1][ar] = av.y;
      As[ac + 2][ar] = av.z;
      As[ac + 3][ar] = av.w;
      __syncthreads();
#pragma unroll
      for (int kk = 0; kk < 16; ++kk) {
        float4 a = *(const float4*)&As[kk][ty * 4];
        float4 b = *(const float4*)&Bs[kk][tx * 4];
        float aa[4] = {a.x, a.y, a.z, a.w};
        float bb[4] = {b.x, b.y, b.z, b.w};
#pragma unroll
        for (int i = 0; i < 4; ++i)
#pragma unroll
          for (int j = 0; j < 4; ++j)
            acc[i][j] = __fadd_rn(acc[i][j], __fmul_rn(aa[i], bb[j]));
      }
      __syncthreads();
    }
#pragma unroll
    for (int i = 0; i < 4; ++i)
#pragma unroll
      for (int j = 0; j < 4; ++j) {
        tot[i][j] = __fadd_rn(tot[i][j], acc[i][j]);  // panel sums in order
        acc[i][j] = 0.f;
      }
  }

#pragma unroll
  for (int i = 0; i < 4; ++i) {
    const int m = m0 + ty * 4 + i;
#pragma unroll
    for (int j = 0; j < 4; ++j) {
      const int n = n0 + tx * 4 + j;
      const float val = __fadd_rn(tot[i][j], bias[n]);
      if (MODE == 0) {
        out[(size_t)m * EMB + n] = val;
      } else {
        const int b = m >> 11, s = m & (SEQ - 1);
        const int h = n >> 6,  d = n & (HD - 1);
        out[((((size_t)b * NHEAD + h) * SEQ) + s) * HD + d] = val;
      }
    }
  }
}

// ---------------------------------------------------------------------------
// FMA f32 GEMM (VALUE PATH — v and out projections; precision-free).
// Explicit fmaf -> v_fmac at 2x the mul+add rate.
// ---------------------------------------------------------------------------
template<int MODE>
__global__ __launch_bounds__(256)
void gemm_fma(const float* __restrict__ A, const float* __restrict__ W,
              const float* __restrict__ bias, float* __restrict__ out) {
  __shared__ float As[16][68];
  __shared__ float Bs[16][68];
  const int m0 = blockIdx.x * 64;
  const int n0 = blockIdx.y * 64;
  const int t  = threadIdx.x;
  const int tx = t & 15, ty = t >> 4;
  const int ar = t >> 2, ac = (t & 3) * 4;
  const int br = t >> 4, bc = (t & 15) * 4;

  float acc[4][4] = {};

  for (int k0 = 0; k0 < EMB; k0 += 16) {
    float4 av = *(const float4*)&A[(size_t)(m0 + ar) * EMB + k0 + ac];
    *(float4*)&Bs[br][bc] = *(const float4*)&W[(size_t)(k0 + br) * EMB + n0 + bc];
    As[ac + 0][ar] = av.x;
    As[ac + 1][ar] = av.y;
    As[ac + 2][ar] = av.z;
    As[ac + 3][ar] = av.w;
    __syncthreads();
#pragma unroll
    for (int kk = 0; kk < 16; ++kk) {
      float4 a = *(const float4*)&As[kk][ty * 4];
      float4 b = *(const float4*)&Bs[kk][tx * 4];
      float aa[4] = {a.x, a.y, a.z, a.w};
      float bb[4] = {b.x, b.y, b.z, b.w};
#pragma unroll
      for (int i = 0; i < 4; ++i)
#pragma unroll
        for (int j = 0; j < 4; ++j)
          acc[i][j] = fmaf(aa[i], bb[j], acc[i][j]);
    }
    __syncthreads();
  }

#pragma unroll
  for (int i = 0; i < 4; ++i) {
    const int m = m0 + ty * 4 + i;
#pragma unroll
    for (int j = 0; j < 4; ++j) {
      const int n = n0 + tx * 4 + j;
      const float val = acc[i][j] + bias[n];
      if (MODE == 0) {
        out[(size_t)m * EMB + n] = val;
      } else {
        const int b = m >> 11, s = m & (SEQ - 1);
        const int h = n >> 6,  d = n & (HD - 1);
        out[((((size_t)b * NHEAD + h) * SEQ) + s) * HD + d] = val;
      }
    }
  }
}

// ---------------------------------------------------------------------------
// Pruning + sparse attention, wave-parallel (r8 structure, bit-proven:
// absmax 0.0078125 == r6). This round: occupancy fix only —
//   * #pragma unroll caps on dot loops (load scheduling only; the
//     fma/add accumulation chains stay d-ascending sequential -> bit-identical)
//   * per-query PV store (no accv[4] live array)
//   * __launch_bounds__(256, 6): <=85 VGPR, 6 waves/SIMD target
//   * XCD-swizzled blockIdx: each XCD's L2 keeps K+V of its own 4 (b,h)
// ---------------------------------------------------------------------------
__device__ __forceinline__ float dot_fma64(const float* qrow, const float* kr) {
  float sc = 0.f;
#pragma unroll 4
  for (int u = 0; u < 16; ++u) {
    const float4 kv = *(const float4*)&kr[u * 4];
    const float4 qv = *(const float4*)&qrow[u * 4];
    sc = fmaf(qv.x, kv.x, sc);
    sc = fmaf(qv.y, kv.y, sc);
    sc = fmaf(qv.z, kv.z, sc);
    sc = fmaf(qv.w, kv.w, sc);
  }
  return sc;
}

template<int CS>
__device__ __forceinline__ void prune_level(const float* kb, const float* qrow,
                                            int qi, int c,
                                            const short* cur, short* nxt) {
  const int rep = cur[qi * 256 + c * CS + (CS >> 1)];
  const float sc = dot_fma64(qrow, kb + (size_t)rep * HD);
  float sv = sc;
#pragma unroll
  for (int r = 0; r < 8; ++r) {
    float v0 = sv; int i0 = c;
#pragma unroll
    for (int off = 1; off < 16; off <<= 1) {
      const float v1 = __shfl_xor(v0, off);
      const int   i1 = __shfl_xor(i0, off);
      if (v1 > v0 || (v1 == v0 && i1 < i0)) { v0 = v1; i0 = i1; }
    }
    if (c < CS) nxt[qi * 256 + r * CS + c] = cur[qi * 256 + i0 * CS + c];
    if (c == i0) sv = -INFINITY;
  }
}

__global__ __launch_bounds__(256, 6)
void prune_attn4(const float* q, const float* k,
                 const float* v, float* ctx) {
  // XCD-aware swizzle: 4096 blocks = 8 XCDs x 512; give each XCD a
  // contiguous logical range (4 full (b,h) groups -> K+V ~ 4MB ~ one L2).
  const int blk  = (blockIdx.x & 7) * 512 + (blockIdx.x >> 3);
  const int tile = blk & 127;             // 16-query tile within (b,h)
  const int bh   = blk >> 7;
  const int wv   = threadIdx.x >> 6;
  const int lane = threadIdx.x & 63;
  const int qg   = wv * 4;                // this wave's query-slot base
  const int s0   = tile * 16 + qg;        // first seq pos of this wave

  const float* kb = k + (size_t)bh * SEQ * HD;
  const float* vb = v + (size_t)bh * SEQ * HD;
  const float* qb = q + ((size_t)bh * SEQ + s0) * HD;

  __shared__ float q_lds[16][68];         // row stride 272B (16B aligned)
  __shared__ short idx_a[16 * 256];
  __shared__ short idx_b[16 * 256];

#pragma unroll
  for (int qq = 0; qq < 4; ++qq)
    q_lds[qg + qq][lane] = qb[(size_t)qq * HD + lane];
  LDS_FENCE();

  // ---- level 0: lane = chunk, 4 query chains interleaved (mul+add, d asc).
  //      unroll 2: limits in-flight kv loads; chain order unchanged. ----
  float sc0[4] = {0.f, 0.f, 0.f, 0.f};
  {
    const float* krep = kb + (size_t)(lane * 32 + 16) * HD;
#pragma unroll 2
    for (int u = 0; u < 16; ++u) {
      const float4 kv = *(const float4*)&krep[u * 4];
#pragma unroll
      for (int qq = 0; qq < 4; ++qq) {
        const float4 qv = *(const float4*)&q_lds[qg + qq][u * 4];
        sc0[qq] = __fadd_rn(sc0[qq], __fmul_rn(qv.x, kv.x));
        sc0[qq] = __fadd_rn(sc0[qq], __fmul_rn(qv.y, kv.y));
        sc0[qq] = __fadd_rn(sc0[qq], __fmul_rn(qv.z, kv.z));
        sc0[qq] = __fadd_rn(sc0[qq], __fmul_rn(qv.w, kv.w));
      }
    }
  }

  // ---- top-8 of 64 per query (butterfly == serial scan, r8-proven) ----
#pragma unroll
  for (int qq = 0; qq < 4; ++qq) {
    float sv = sc0[qq];
#pragma unroll
    for (int r = 0; r < 8; ++r) {
      float v0 = sv; int i0 = lane;
#pragma unroll
      for (int off = 32; off; off >>= 1) {
        const float v1 = __shfl_xor(v0, off);
        const int   i1 = __shfl_xor(i0, off);
        if (v1 > v0 || (v1 == v0 && i1 < i0)) { v0 = v1; i0 = i1; }
      }
      if (lane < 32) idx_a[(qg + qq) * 256 + r * 32 + lane] = (short)(i0 * 32 + lane);
      if (lane == i0) sv = -INFINITY;
    }
  }
  LDS_FENCE();

  // ---- pruning levels: lane = (query, candidate) ----
  const int qq2  = lane >> 4;
  const int c    = lane & 15;
  const int qi   = qg + qq2;
  const float* qrow = &q_lds[qi][0];

  prune_level<16>(kb, qrow, qi, c, idx_a, idx_b);
  LDS_FENCE();
  prune_level< 8>(kb, qrow, qi, c, idx_b, idx_a);
  LDS_FENCE();
  prune_level< 4>(kb, qrow, qi, c, idx_a, idx_b);
  LDS_FENCE();
  prune_level< 2>(kb, qrow, qi, c, idx_b, idx_a);
  LDS_FENCE();

  // ---- final: 16 keys, sequential FMA dot, scale 1/8 ----
  const int kidx = idx_a[qi * 256 + c];
  const float sfin = __fmul_rn(dot_fma64(qrow, kb + (size_t)kidx * HD), 0.125f);

  // ---- softmax over each 16-lane group (value path) ----
  float mx = sfin;
#pragma unroll
  for (int off = 1; off < 16; off <<= 1) mx = fmaxf(mx, __shfl_xor(mx, off));
  const float e = expf(sfin - mx);
  float sum = e;
#pragma unroll
  for (int off = 1; off < 16; off <<= 1) sum += __shfl_xor(sum, off);

  // ---- PV: per-query pass, lane owns dim d; store immediately ----
  const int b = bh >> 4, h = bh & 15;
#pragma unroll
  for (int qq = 0; qq < 4; ++qq) {
    float acc = 0.f;
#pragma unroll
    for (int j = 0; j < 16; ++j) {
      const float ej = __shfl(e,    qq * 16 + j);
      const float sm = __shfl(sum,  qq * 16 + j);
      const int   kj = __shfl(kidx, qq * 16 + j);
      acc = fmaf(__fdiv_rn(ej, sm), vb[(size_t)kj * HD + lane], acc);
    }
    ctx[((size_t)b * SEQ + (s0 + qq)) * EMB + h * HD + lane] = acc;
  }
}

// ---------------------------------------------------------------------------
extern "C" void kernel_launch(void* const* d_in, const int* in_sizes, int n_in,
                              void* d_out, int out_size, void* d_ws, size_t ws_size,
                              hipStream_t stream) {
  const float* x  = (const float*)d_in[0];
  const float* Wq = (const float*)d_in[1];
  const float* bq = (const float*)d_in[2];
  const float* Wk = (const float*)d_in[3];
  const float* bk = (const float*)d_in[4];
  const float* Wv = (const float*)d_in[5];
  const float* bv = (const float*)d_in[6];
  const float* Wo = (const float*)d_in[7];
  const float* bo = (const float*)d_in[8];
  float* out = (float*)d_out;

  const size_t SZ = (size_t)BATCH * NHEAD * SEQ * HD;  // 4,194,304
  float* qw = (float*)d_ws;
  float* kw = qw + SZ;
  float* vw = kw + SZ;
  float* cw = vw + SZ;   // ctx in [B,S,E] layout

  dim3 g(64, 16), blk(256);
  gemm_eigen<1><<<g, blk, 0, stream>>>(x, Wq, bq, qw);
  gemm_eigen<1><<<g, blk, 0, stream>>>(x, Wk, bk, kw);
  gemm_fma<1><<<g, blk, 0, stream>>>(x, Wv, bv, vw);
  prune_attn4<<<dim3(BATCH * NHEAD * (SEQ / 16)), blk, 0, stream>>>(qw, kw, vw, cw);
  gemm_fma<0><<<g, blk, 0, stream>>>(cw, Wo, bo, out);
}

// Round 10
// 676.175 us; speedup vs baseline: 1.8899x; 1.0777x over previous
//
#include <hip/hip_runtime.h>
#include <math.h>

#define BATCH 2
#define NHEAD 16
#define SEQ   2048
#define HD    64
#define EMB   1024

typedef float v2f __attribute__((ext_vector_type(2)));

// Compiler-only memory fence (r7 post-mortem): wave-private LDS phases need
// compile-time ordering only; hardware DS is in-order per wave.
#define LDS_FENCE() asm volatile("" ::: "memory")

// ---------------------------------------------------------------------------
// Eigen-AVX-emulating f32 GEMM (DECISION PATH — r9 verbatim, bit-frozen):
// 4 k-panels of 256, sequential mul-then-add within panel, panels summed in
// order, + bias. __fmul_rn/__fadd_rn defeat fp-contract.
// ---------------------------------------------------------------------------
template<int MODE>
__global__ __launch_bounds__(256)
void gemm_eigen(const float* __restrict__ A, const float* __restrict__ W,
                const float* __restrict__ bias, float* __restrict__ out) {
  __shared__ float As[16][68];
  __shared__ float Bs[16][68];
  const int m0 = blockIdx.x * 64;
  const int n0 = blockIdx.y * 64;
  const int t  = threadIdx.x;
  const int tx = t & 15, ty = t >> 4;
  const int ar = t >> 2, ac = (t & 3) * 4;
  const int br = t >> 4, bc = (t & 15) * 4;

  float tot[4][4] = {};
  float acc[4][4] = {};

  for (int p = 0; p < 4; ++p) {
    for (int kt = 0; kt < 16; ++kt) {
      const int k0 = p * 256 + kt * 16;
      float4 av = *(const float4*)&A[(size_t)(m0 + ar) * EMB + k0 + ac];
      *(float4*)&Bs[br][bc] = *(const float4*)&W[(size_t)(k0 + br) * EMB + n0 + bc];
      As[ac + 0][ar] = av.x;
      As[ac + 1][ar] = av.y;
      As[ac + 2][ar] = av.z;
      As[ac + 3][ar] = av.w;
      __syncthreads();
#pragma unroll
      for (int kk = 0; kk < 16; ++kk) {
        float4 a = *(const float4*)&As[kk][ty * 4];
        float4 b = *(const float4*)&Bs[kk][tx * 4];
        float aa[4] = {a.x, a.y, a.z, a.w};
        float bb[4] = {b.x, b.y, b.z, b.w};
#pragma unroll
        for (int i = 0; i < 4; ++i)
#pragma unroll
          for (int j = 0; j < 4; ++j)
            acc[i][j] = __fadd_rn(acc[i][j], __fmul_rn(aa[i], bb[j]));
      }
      __syncthreads();
    }
#pragma unroll
    for (int i = 0; i < 4; ++i)
#pragma unroll
      for (int j = 0; j < 4; ++j) {
        tot[i][j] = __fadd_rn(tot[i][j], acc[i][j]);
        acc[i][j] = 0.f;
      }
  }

#pragma unroll
  for (int i = 0; i < 4; ++i) {
    const int m = m0 + ty * 4 + i;
#pragma unroll
    for (int j = 0; j < 4; ++j) {
      const int n = n0 + tx * 4 + j;
      const float val = __fadd_rn(tot[i][j], bias[n]);
      if (MODE == 0) {
        out[(size_t)m * EMB + n] = val;
      } else {
        const int b = m >> 11, s = m & (SEQ - 1);
        const int h = n >> 6,  d = n & (HD - 1);
        out[((((size_t)b * NHEAD + h) * SEQ) + s) * HD + d] = val;
      }
    }
  }
}

// ---------------------------------------------------------------------------
// Packed-FMA f32 GEMM (VALUE PATH — v / out projections). v_pk_fma_f32 does
// two independent IEEE fmas per inst; per-element k-chain order unchanged
// (bit-identical to scalar fmaf version). op_sel broadcasts the A scalar.
// ---------------------------------------------------------------------------
template<int MODE>
__global__ __launch_bounds__(256)
void gemm_fma_pk(const float* __restrict__ A, const float* __restrict__ W,
                 const float* __restrict__ bias, float* __restrict__ out) {
  __shared__ float As[16][68];
  __shared__ float Bs[16][68];
  const int m0 = blockIdx.x * 64;
  const int n0 = blockIdx.y * 64;
  const int t  = threadIdx.x;
  const int tx = t & 15, ty = t >> 4;
  const int ar = t >> 2, ac = (t & 3) * 4;
  const int br = t >> 4, bc = (t & 15) * 4;

  v2f acc2[4][2] = {};   // acc2[i][jp] = cols (4tx+2jp, 4tx+2jp+1), row 4ty+i

  for (int k0 = 0; k0 < EMB; k0 += 16) {
    float4 av = *(const float4*)&A[(size_t)(m0 + ar) * EMB + k0 + ac];
    *(float4*)&Bs[br][bc] = *(const float4*)&W[(size_t)(k0 + br) * EMB + n0 + bc];
    As[ac + 0][ar] = av.x;
    As[ac + 1][ar] = av.y;
    As[ac + 2][ar] = av.z;
    As[ac + 3][ar] = av.w;
    __syncthreads();
#pragma unroll
    for (int kk = 0; kk < 16; ++kk) {
      v2f a01 = *(const v2f*)&As[kk][ty * 4];
      v2f a23 = *(const v2f*)&As[kk][ty * 4 + 2];
      v2f b01 = *(const v2f*)&Bs[kk][tx * 4];
      v2f b23 = *(const v2f*)&Bs[kk][tx * 4 + 2];
      // row 0: a01.lo broadcast; row 1: a01.hi; row 2: a23.lo; row 3: a23.hi
      asm volatile("v_pk_fma_f32 %0, %1, %2, %0 op_sel:[0,0,0] op_sel_hi:[0,1,1]"
                   : "+v"(acc2[0][0]) : "v"(a01), "v"(b01));
      asm volatile("v_pk_fma_f32 %0, %1, %2, %0 op_sel:[0,0,0] op_sel_hi:[0,1,1]"
                   : "+v"(acc2[0][1]) : "v"(a01), "v"(b23));
      asm volatile("v_pk_fma_f32 %0, %1, %2, %0 op_sel:[1,0,0] op_sel_hi:[1,1,1]"
                   : "+v"(acc2[1][0]) : "v"(a01), "v"(b01));
      asm volatile("v_pk_fma_f32 %0, %1, %2, %0 op_sel:[1,0,0] op_sel_hi:[1,1,1]"
                   : "+v"(acc2[1][1]) : "v"(a01), "v"(b23));
      asm volatile("v_pk_fma_f32 %0, %1, %2, %0 op_sel:[0,0,0] op_sel_hi:[0,1,1]"
                   : "+v"(acc2[2][0]) : "v"(a23), "v"(b01));
      asm volatile("v_pk_fma_f32 %0, %1, %2, %0 op_sel:[0,0,0] op_sel_hi:[0,1,1]"
                   : "+v"(acc2[2][1]) : "v"(a23), "v"(b23));
      asm volatile("v_pk_fma_f32 %0, %1, %2, %0 op_sel:[1,0,0] op_sel_hi:[1,1,1]"
                   : "+v"(acc2[3][0]) : "v"(a23), "v"(b01));
      asm volatile("v_pk_fma_f32 %0, %1, %2, %0 op_sel:[1,0,0] op_sel_hi:[1,1,1]"
                   : "+v"(acc2[3][1]) : "v"(a23), "v"(b23));
    }
    __syncthreads();
  }

#pragma unroll
  for (int i = 0; i < 4; ++i) {
    const int m = m0 + ty * 4 + i;
#pragma unroll
    for (int jp = 0; jp < 2; ++jp)
#pragma unroll
      for (int hh = 0; hh < 2; ++hh) {
        const int n = n0 + tx * 4 + jp * 2 + hh;
        const float val = acc2[i][jp][hh] + bias[n];
        if (MODE == 0) {
          out[(size_t)m * EMB + n] = val;
        } else {
          const int b = m >> 11, s = m & (SEQ - 1);
          const int h = n >> 6,  d = n & (HD - 1);
          out[((((size_t)b * NHEAD + h) * SEQ) + s) * HD + d] = val;
        }
      }
  }
}

// ---------------------------------------------------------------------------
// Pruning + sparse attention v5: rank-based selection (exact-equivalent to
// serial scan under total order (value desc, index asc); pure compares, no
// FP changes), single-buffer idx, LDS-broadcast PV. Score arithmetic is
// byte-identical to r9 (level-0 mul+add d-asc; level/final dots fma d-asc).
// ---------------------------------------------------------------------------
__device__ __forceinline__ float dot_fma64(const float* qrow, const float* kr) {
  float sc = 0.f;
#pragma unroll 4
  for (int u = 0; u < 16; ++u) {
    const float4 kv = *(const float4*)&kr[u * 4];
    const float4 qv = *(const float4*)&qrow[u * 4];
    sc = fmaf(qv.x, kv.x, sc);
    sc = fmaf(qv.y, kv.y, sc);
    sc = fmaf(qv.z, kv.z, sc);
    sc = fmaf(qv.w, kv.w, sc);
  }
  return sc;
}

template<int CS>
__device__ __forceinline__ void level5(const float* kb, const float* qrow,
                                       int qi, int c,
                                       float (*scr)[66], short (*idx)[256],
                                       int (*sel)[8]) {
  const int rep = idx[qi][c * CS + (CS >> 1)];
  const float sv = dot_fma64(qrow, kb + (size_t)rep * HD);
  scr[qi][c] = sv;
  LDS_FENCE();
  int cnt = 0;
#pragma unroll
  for (int c2 = 0; c2 < 16; ++c2) {
    const float vv = scr[qi][c2];
    cnt += (vv > sv) || (vv == sv && c2 < c) ? 1 : 0;
  }
  if (cnt < 8) sel[qi][cnt] = c;   // exactly 8 lanes write (ranks unique)
  LDS_FENCE();
  // expansion: new list len 8*CS, E = CS/2 entries per lane (16 lanes/query)
  short tmp[CS / 2];
#pragma unroll
  for (int e = 0; e < CS / 2; ++e) {
    const int p = c * (CS / 2) + e;
    tmp[e] = idx[qi][sel[qi][p / CS] * CS + (p % CS)];
  }
  LDS_FENCE();   // lockstep wave: all reads above retire before writes below
#pragma unroll
  for (int e = 0; e < CS / 2; ++e)
    idx[qi][c * (CS / 2) + e] = tmp[e];
  LDS_FENCE();
}

__global__ __launch_bounds__(256, 8)
void prune_attn5(const float* q, const float* k,
                 const float* v, float* ctx) {
  const int blk  = (blockIdx.x & 7) * 512 + (blockIdx.x >> 3);  // XCD swizzle
  const int tile = blk & 127;
  const int bh   = blk >> 7;
  const int wv   = threadIdx.x >> 6;
  const int lane = threadIdx.x & 63;
  const int qg   = wv * 4;
  const int s0   = tile * 16 + qg;

  const float* kb = k + (size_t)bh * SEQ * HD;
  const float* vb = v + (size_t)bh * SEQ * HD;
  const float* qb = q + ((size_t)bh * SEQ + s0) * HD;

  __shared__ float q_lds[16][68];
  __shared__ float scr[16][66];     // level-0 scores(64) -> level scores(16) -> w(16)
  __shared__ short idx[16][256];    // single-buffer candidate list
  __shared__ int   sel[16][8];
  __shared__ short kfin[16][16];

#pragma unroll
  for (int qq = 0; qq < 4; ++qq)
    q_lds[qg + qq][lane] = qb[(size_t)qq * HD + lane];
  LDS_FENCE();

  // ---- level 0: lane = chunk; 4 query chains, mul+add d-ascending ----
  float sc0[4] = {0.f, 0.f, 0.f, 0.f};
  {
    const float* krep = kb + (size_t)(lane * 32 + 16) * HD;
#pragma unroll 2
    for (int u = 0; u < 16; ++u) {
      const float4 kv = *(const float4*)&krep[u * 4];
#pragma unroll
      for (int qq = 0; qq < 4; ++qq) {
        const float4 qv = *(const float4*)&q_lds[qg + qq][u * 4];
        sc0[qq] = __fadd_rn(sc0[qq], __fmul_rn(qv.x, kv.x));
        sc0[qq] = __fadd_rn(sc0[qq], __fmul_rn(qv.y, kv.y));
        sc0[qq] = __fadd_rn(sc0[qq], __fmul_rn(qv.z, kv.z));
        sc0[qq] = __fadd_rn(sc0[qq], __fmul_rn(qv.w, kv.w));
      }
    }
  }
#pragma unroll
  for (int qq = 0; qq < 4; ++qq)
    scr[qg + qq][lane] = sc0[qq];
  LDS_FENCE();

  // ---- rank-based top-8 of 64 per query (parallel, no serial chains) ----
  {
    int cnt[4] = {0, 0, 0, 0};
#pragma unroll 8
    for (int c2 = 0; c2 < 64; ++c2) {
#pragma unroll
      for (int qq = 0; qq < 4; ++qq) {
        const float vv = scr[qg + qq][c2];   // broadcast read
        cnt[qq] += (vv > sc0[qq]) || (vv == sc0[qq] && c2 < lane) ? 1 : 0;
      }
    }
#pragma unroll
    for (int qq = 0; qq < 4; ++qq)
      if (cnt[qq] < 8) sel[qg + qq][cnt[qq]] = lane;
  }
  LDS_FENCE();

  // ---- idx fill: 256 entries/query, 4 per lane, packed 8B writes ----
#pragma unroll
  for (int qq = 0; qq < 4; ++qq) {
    const int p0   = lane * 4;
    const int base = sel[qg + qq][p0 >> 5] * 32 + (p0 & 31);
    uint2 pk;
    pk.x = (unsigned)(base & 0xffff) | ((unsigned)(base + 1) << 16);
    pk.y = (unsigned)((base + 2) & 0xffff) | ((unsigned)(base + 3) << 16);
    *(uint2*)&idx[qg + qq][p0] = pk;
  }
  LDS_FENCE();

  // ---- pruning levels: lane = (query, candidate) ----
  const int c  = lane & 15;
  const int qi = qg + (lane >> 4);
  const float* qrow = &q_lds[qi][0];

  level5<16>(kb, qrow, qi, c, scr, idx, sel);
  level5< 8>(kb, qrow, qi, c, scr, idx, sel);
  level5< 4>(kb, qrow, qi, c, scr, idx, sel);
  level5< 2>(kb, qrow, qi, c, scr, idx, sel);

  // ---- final: 16 keys, sequential FMA dot, scale 1/8 ----
  const int kidx = idx[qi][c];
  const float sfin = __fmul_rn(dot_fma64(qrow, kb + (size_t)kidx * HD), 0.125f);

  // ---- softmax over 16-lane group (butterfly, r9 value-path verbatim) ----
  float mx = sfin;
#pragma unroll
  for (int off = 1; off < 16; off <<= 1) mx = fmaxf(mx, __shfl_xor(mx, off));
  const float e = expf(sfin - mx);
  float sum = e;
#pragma unroll
  for (int off = 1; off < 16; off <<= 1) sum += __shfl_xor(sum, off);
  const float w = __fdiv_rn(e, sum);   // same quotient as r9's per-consumer div

  scr[qi][c]  = w;
  kfin[qi][c] = (short)kidx;
  LDS_FENCE();

  // ---- PV: lane owns dim d; w/kidx broadcast from LDS; j order as r9 ----
  const int b = bh >> 4, h = bh & 15;
#pragma unroll
  for (int qq = 0; qq < 4; ++qq) {
    const int qi2 = qg + qq;
    float acc = 0.f;
#pragma unroll
    for (int j = 0; j < 16; ++j)
      acc = fmaf(scr[qi2][j], vb[(size_t)kfin[qi2][j] * HD + lane], acc);
    ctx[((size_t)b * SEQ + (s0 + qq)) * EMB + h * HD + lane] = acc;
  }
}

// ---------------------------------------------------------------------------
extern "C" void kernel_launch(void* const* d_in, const int* in_sizes, int n_in,
                              void* d_out, int out_size, void* d_ws, size_t ws_size,
                              hipStream_t stream) {
  const float* x  = (const float*)d_in[0];
  const float* Wq = (const float*)d_in[1];
  const float* bq = (const float*)d_in[2];
  const float* Wk = (const float*)d_in[3];
  const float* bk = (const float*)d_in[4];
  const float* Wv = (const float*)d_in[5];
  const float* bv = (const float*)d_in[6];
  const float* Wo = (const float*)d_in[7];
  const float* bo = (const float*)d_in[8];
  float* out = (float*)d_out;

  const size_t SZ = (size_t)BATCH * NHEAD * SEQ * HD;
  float* qw = (float*)d_ws;
  float* kw = qw + SZ;
  float* vw = kw + SZ;
  float* cw = vw + SZ;

  dim3 g(64, 16), blk(256);
  gemm_eigen<1><<<g, blk, 0, stream>>>(x, Wq, bq, qw);
  gemm_eigen<1><<<g, blk, 0, stream>>>(x, Wk, bk, kw);
  gemm_fma_pk<1><<<g, blk, 0, stream>>>(x, Wv, bv, vw);
  prune_attn5<<<dim3(BATCH * NHEAD * (SEQ / 16)), blk, 0, stream>>>(qw, kw, vw, cw);
  gemm_fma_pk<0><<<g, blk, 0, stream>>>(cw, Wo, bo, out);
}